// Round 7
// baseline (138.733 us; speedup 1.0000x reference)
//
#include <hip/hip_runtime.h>

// ST-GCN fused block for MI355X (gfx950).  FP32 I/O, bf16 at MFMA boundaries.
// 3 dispatches: kwin(+prep) -> kmain (4-l blocks, single 26.6 KB T1, 4 blk/CU,
//               both-pair B-frag prefetch, per-i acc repack; stats atomics)
//            -> kapply (vectorized stats reduce + XOR-swizzled zl transpose +
//               BN+ReLU+residual, f32x4).
// xs layout: [n][l][25 v][64 ci] bf16.   zb layout: [n][l][w][c] bf16.
// statsbuf: 128 copies x 128 f32 -> 8 atomics/address.

typedef unsigned short ushort_t;
typedef __attribute__((ext_vector_type(8))) short short8;   // 8 x bf16 MFMA frag
typedef __attribute__((ext_vector_type(4))) float f32x4;
typedef __attribute__((ext_vector_type(4))) unsigned short us4;

#define N_  4
#define CI_ 64
#define CO_ 64
#define L_  1024
#define V_  25
#define P_  3
#define KS_ 9
#define NLV 102400.0f   // N_*L_*V_  (BN population count per channel)
#define NREP 128        // stats replication factor
#define TSTR 406        // kwin tile row stride (hw); even (u32 ok), 203 dw odd

__device__ __forceinline__ float b2f(ushort_t u) {
  union { float f; unsigned int i; } c; c.i = ((unsigned int)u) << 16; return c.f;
}
__device__ __forceinline__ ushort_t f2b(float f) {
  union { float f; unsigned int i; } c; c.f = f;
  unsigned int u = c.i;
  u += 0x7fffu + ((u >> 16) & 1u);      // round-to-nearest-even
  return (ushort_t)(u >> 16);
}

// ---------------------------------------------------------------------------
// kwin: causal 9-wide window-sum along l, fp32 x -> bf16 xs[n][l][25*64].
// block = (chunk of 8 l's, n); chunk==128 & n==0 does prep instead.
__global__ __launch_bounds__(256) void kwin(
    const float* __restrict__ x, ushort_t* __restrict__ xs,
    const float* __restrict__ A, const float* __restrict__ E,
    const float* __restrict__ cb, const float* __restrict__ W,
    ushort_t* __restrict__ a2raw, float* __restrict__ biastab,
    ushort_t* __restrict__ wb, float* __restrict__ statsbuf)
{
  const int chunk = blockIdx.x;                 // 0..128
  const int n = blockIdx.y;
  const int tid = threadIdx.x;

  if (chunk == 128) {                           // ---- prep block ----
    if (n != 0) return;
    __shared__ float colA[P_ * 32];
    if (tid < P_ * 32) {
      int p = tid >> 5, w = tid & 31;
      float s = 0.f;
      if (w < V_)
        for (int v = 0; v < V_; ++v) {
          int idx = (p * V_ + v) * V_ + w;
          s += A[idx] * E[idx];
        }
      colA[tid] = s;
    }
    for (int e = tid; e < 32 * 96; e += 256) {
      int w = e / 96, k = e - w * 96;
      int p = k >> 5, v = k & 31;
      float val = 0.f;
      if (w < V_ && v < V_) {
        int idx = (p * V_ + v) * V_ + w;
        val = A[idx] * E[idx];
      }
      a2raw[e] = f2b(val);
    }
    for (int e = tid; e < 192 * 64; e += 256) wb[e] = f2b(W[e]);
    __syncthreads();
    for (int e = tid; e < 32 * 64; e += 256) {
      int w = e >> 6, c = e & 63;
      float s = 0.f;
      for (int p = 0; p < P_; ++p) s += cb[p * 64 + c] * colA[p * 32 + w];
      biastab[e] = s;
    }
    for (int e = tid; e < NREP * 128; e += 256) statsbuf[e] = 0.f;
    return;
  }

  // ---- window block ----
  __shared__ __align__(16) ushort_t tile[64 * TSTR];  // 52 KB
  const int l0 = chunk * 8;
  const long xn = (long)n * CI_ * L_ * V_;
  for (int m = tid; m < 6400; m += 256) {       // 64 ci x 400 f32 -> bf16
    int ci = m / 100;
    int j4 = (m - ci * 100) * 4;                // 0..396
    f32x4 d;
    if (chunk == 0 && j4 < 200) {
      d = (f32x4){0.f, 0.f, 0.f, 0.f};          // l < 0 halo (li 0..7)
    } else {
      d = *(const f32x4*)(x + xn + (long)ci * (L_ * V_) + (l0 - 8) * V_ + j4);
    }
    unsigned int p0 = (unsigned int)f2b(d[0]) | ((unsigned int)f2b(d[1]) << 16);
    unsigned int p1 = (unsigned int)f2b(d[2]) | ((unsigned int)f2b(d[3]) << 16);
    *(unsigned int*)(&tile[ci * TSTR + j4])     = p0;
    *(unsigned int*)(&tile[ci * TSTR + j4 + 2]) = p1;
  }
  __syncthreads();
  // sliding window per (v, ci-pair) column; coalesced u32 stores per l_.
  const long xsbase = ((long)n * L_ + l0) * 1600;
  for (int cp = tid; cp < 800; cp += 256) {
    const int v = cp >> 5, ci = (cp & 31) * 2;
    const ushort_t* c0 = &tile[ci * TSTR + v];  // + li*25 steps along l
    const ushort_t* c1 = c0 + TSTR;
    float s0 = 0.f, s1 = 0.f;
#pragma unroll
    for (int li = 0; li < 9; ++li) { s0 += b2f(c0[li * 25]); s1 += b2f(c1[li * 25]); }
    *(unsigned int*)(xs + xsbase + v * 64 + ci) =
        (unsigned int)f2b(s0) | ((unsigned int)f2b(s1) << 16);
#pragma unroll
    for (int l_ = 1; l_ < 8; ++l_) {
      s0 += b2f(c0[(l_ + 8) * 25]) - b2f(c0[(l_ - 1) * 25]);
      s1 += b2f(c1[(l_ + 8) * 25]) - b2f(c1[(l_ - 1) * 25]);
      *(unsigned int*)(xs + xsbase + l_ * 1600 + v * 64 + ci) =
          (unsigned int)f2b(s0) | ((unsigned int)f2b(s1) << 16);
    }
  }
}

// ---------------------------------------------------------------------------
// kmain: per-(n, 4 l's) block; single 26.6 KB T1, 3 barriers, 4 blocks/CU.
//   ALL 16 xs B-frags (both pairs) prefetched upfront (latency overlap).
//   per pair: stage1 (per-i acc -> T1 repack), stage2, epilogue (zb + stats).
__global__ __launch_bounds__(256, 4) void kmain(
    const ushort_t* __restrict__ xs,      // [n][l][1600] bf16 (L2-hot)
    const ushort_t* __restrict__ Wb,      // [192][64] bf16 (L1-hot)
    const ushort_t* __restrict__ a2,      // [32 w][96 k] bf16 (L1-hot)
    const float*    __restrict__ biastab, // [32 w][64 c] f32 (L1-hot)
    ushort_t*       __restrict__ zb,
    float*          __restrict__ statsbuf)
{
  const int lb = blockIdx.x;            // 4 l's per block (0..255)
  const int n  = blockIdx.y;
  const int tid = threadIdx.x, lane = tid & 63, wv = tid >> 6;
  const int m16 = lane & 15, quad = lane >> 4;

  __shared__ __align__(16) ushort_t T1[13312];   // [l_][c][104]  26.6 KB

  const ushort_t* xsb = xs + ((long)n * L_ + 4 * lb) * 1600;

  // ---- prefetch ALL stage-1 B-frags (16 global loads in flight) ----
  short8 bfr[2][4][2];
#pragma unroll
  for (int pair = 0; pair < 2; ++pair)
#pragma unroll
    for (int nt = 0; nt < 4; ++nt) {
      const int v = (nt & 1) * 16 + m16;
      const int l_ = pair * 2 + (nt >> 1);
#pragma unroll
      for (int ks = 0; ks < 2; ++ks) {
        short8 t = (short8){0, 0, 0, 0, 0, 0, 0, 0};
        if (v < V_)
          t = *(const short8*)(xsb + l_ * 1600 + v * 64 + ks * 32 + quad * 8);
        bfr[pair][nt][ks] = t;
      }
    }

  // hoist Wb A-frags once (reused by both pairs)
  short8 af[3][2];
#pragma unroll
  for (int i = 0; i < 3; ++i) {
    const ushort_t* wrow = Wb + ((wv * 3 + i) * 16 + m16) * 64 + quad * 8;
    af[i][0] = *(const short8*)(wrow);
    af[i][1] = *(const short8*)(wrow + 32);
  }

  const int cbase = wv * 16 + quad * 4;
  float s1[4] = {0.f, 0.f, 0.f, 0.f}, s2[4] = {0.f, 0.f, 0.f, 0.f};

#pragma unroll
  for (int pair = 0; pair < 2; ++pair) {
    if (pair) __syncthreads();          // prior pair's T1 reads complete

    // ---- stage 1: per-i accumulate + repack (low VGPR) ----
#pragma unroll
    for (int i = 0; i < 3; ++i) {
      f32x4 acc[4];
#pragma unroll
      for (int nt = 0; nt < 4; ++nt) acc[nt] = (f32x4){0.f, 0.f, 0.f, 0.f};
#pragma unroll
      for (int nt = 0; nt < 4; ++nt) {
        acc[nt] = __builtin_amdgcn_mfma_f32_16x16x32_bf16(af[i][0], bfr[pair][nt][0], acc[nt], 0, 0, 0);
        acc[nt] = __builtin_amdgcn_mfma_f32_16x16x32_bf16(af[i][1], bfr[pair][nt][1], acc[nt], 0, 0, 0);
      }
      // repack -> T1[l_][c][p*32+v]  (D: row = quad*4+r, col = m16)
      const int mt = wv * 3 + i;
#pragma unroll
      for (int nt = 0; nt < 4; ++nt) {
        const int l_ = nt >> 1;
        const int col = (nt & 1) * 16 + m16;
#pragma unroll
        for (int r = 0; r < 4; ++r) {
          int k = mt * 16 + quad * 4 + r;        // k = p*64 + c
          T1[l_ * 6656 + (k & 63) * 104 + (k >> 6) * 32 + col] = f2b(acc[nt][r]);
        }
      }
    }
    __syncthreads();

    // ---- stage 2: 12 MFMA; a2 B-frags loaded per pair (global, L1-hot) ----
    short8 bfr2[2][3];
#pragma unroll
    for (int nt = 0; nt < 2; ++nt)
#pragma unroll
      for (int ks = 0; ks < 3; ++ks)
        bfr2[nt][ks] = *(const short8*)(a2 + (nt * 16 + m16) * 96 + ks * 32 + quad * 8);

    f32x4 acc2[2][2];
#pragma unroll
    for (int l_ = 0; l_ < 2; ++l_)
#pragma unroll
      for (int nt = 0; nt < 2; ++nt) acc2[l_][nt] = (f32x4){0.f, 0.f, 0.f, 0.f};

#pragma unroll
    for (int l_ = 0; l_ < 2; ++l_)
#pragma unroll
      for (int ks = 0; ks < 3; ++ks) {
        short8 afT = *(const short8*)(&T1[l_ * 6656 + (wv * 16 + m16) * 104 + ks * 32 + quad * 8]);
        acc2[l_][0] = __builtin_amdgcn_mfma_f32_16x16x32_bf16(afT, bfr2[0][ks], acc2[l_][0], 0, 0, 0);
        acc2[l_][1] = __builtin_amdgcn_mfma_f32_16x16x32_bf16(afT, bfr2[1][ks], acc2[l_][1], 0, 0, 0);
      }

    // epilogue: + cnt(l)*bias (float4), us4 store; accumulate BN stats
#pragma unroll
    for (int l_ = 0; l_ < 2; ++l_) {
      const int l = 4 * lb + pair * 2 + l_;
      const float cnt = (float)(l + 1 < KS_ ? l + 1 : KS_);
#pragma unroll
      for (int nt = 0; nt < 2; ++nt) {
        const int w = nt * 16 + m16;
        if (w < V_) {
          f32x4 bias = *(const f32x4*)(biastab + w * 64 + cbase);
          us4 pack;
#pragma unroll
          for (int r = 0; r < 4; ++r) {
            pack[r] = f2b(acc2[l_][nt][r] + cnt * bias[r]);
            float zr = b2f(pack[r]);            // stats on the stored value
            s1[r] += zr; s2[r] += zr * zr;
          }
          *(us4*)(&zb[(((long)(n * L_ + l) * V_ + w) << 6) + cbase]) = pack;
        }
      }
    }
  }
  // in-quad reduction over m16 (lanes of a quad share channels cbase..cbase+3)
#pragma unroll
  for (int off = 1; off < 16; off <<= 1) {
#pragma unroll
    for (int r = 0; r < 4; ++r) {
      s1[r] += __shfl_xor(s1[r], off, 64);
      s2[r] += __shfl_xor(s2[r], off, 64);
    }
  }
  if (m16 == 0) {
    float* sb = statsbuf + ((n * 256 + lb) & (NREP - 1)) * 128;
#pragma unroll
    for (int r = 0; r < 4; ++r) {
      atomicAdd(&sb[cbase + r], s1[r]);
      atomicAdd(&sb[64 + cbase + r], s2[r]);
    }
  }
}

// ---------------------------------------------------------------------------
// kapply: reduce statsbuf copies (f32x4, L2-hot) -> mean/var, then
// out[n,c,l,v] = relu(relu((z-mean)*rstd*g+b) + x).  8 l's per block, f32x4.
// zl uses XOR column swizzle (c ^ ((row>>2 & 31)<<1)) -> ~2-way banks on read.
__global__ __launch_bounds__(256) void kapply(
    const ushort_t* __restrict__ zb, const float* __restrict__ x,
    const float* __restrict__ statsbuf,
    const float* __restrict__ gamma, const float* __restrict__ beta,
    float* __restrict__ out)
{
  const int n = blockIdx.y, chunk = blockIdx.x;   // 8 l's per block
  const int tid = threadIdx.x;
  __shared__ __align__(16) ushort_t zl[200 * 66]; // 26.4 KB transpose staging
  __shared__ f32x4 red[8][32];
  __shared__ float sc[64], sh[64];
  const long zbase = (long)((n * L_ + chunk * 8) * V_) * 64;   // 12800 elems
  for (int m = tid; m < 6400; m += 256) {         // u32 = 2 bf16, swizzled col
    const int row = m >> 5, c2 = (m & 31) * 2;
    const int cs = c2 ^ (((row >> 2) & 31) << 1);
    *(unsigned int*)(&zl[row * 66 + cs]) = ((const unsigned int*)(zb + zbase))[m];
  }
  // reduce the NREP stats copies (64-KB L2-hot region), f32x4
  {
    const int s4 = tid & 31, grp = tid >> 5;      // 8 groups x 32 f32x4 slots
    const f32x4* sb4 = (const f32x4*)statsbuf;
    f32x4 a = (f32x4){0.f, 0.f, 0.f, 0.f};
    for (int k = grp; k < NREP; k += 8) {
      f32x4 v = sb4[k * 32 + s4];
      a[0] += v[0]; a[1] += v[1]; a[2] += v[2]; a[3] += v[3];
    }
    red[grp][s4] = a;
  }
  __syncthreads();
  if (tid < 64) {
    const float inv = 1.0f / NLV;
    float s = 0.f, sq = 0.f;
#pragma unroll
    for (int g = 0; g < 8; ++g) {
      s  += red[g][tid >> 2][tid & 3];
      sq += red[g][16 + (tid >> 2)][tid & 3];
    }
    float mean = s * inv;
    float var  = sq * inv - mean * mean;
    float rstd = rsqrtf(var + 1e-5f);
    float g = gamma[tid];
    sc[tid] = rstd * g;
    sh[tid] = beta[tid] - mean * rstd * g;
  }
  __syncthreads();
  const long obase = ((long)(n * 64) * L_ + chunk * 8) * V_;   // + c*25600 + rr
  for (int m = tid; m < 3200; m += 256) {
    int c = m / 50, q = m - c * 50, rr = q * 4;   // rr = 4-aligned l*25+v
    const int e = ((q & 31) << 1);                // (rr+j)>>2 == q for j<4
    long xi = obase + (long)c * (L_ * V_) + rr;
    f32x4 xv = *(const f32x4*)(x + xi);
    const float scc = sc[c], shc = sh[c];
    f32x4 o;
#pragma unroll
    for (int j = 0; j < 4; ++j) {
      float z = b2f(zl[(rr + j) * 66 + (c ^ e)]);
      float y = fmaxf(z * scc + shc, 0.f);
      o[j] = fmaxf(y + xv[j], 0.f);
    }
    *(f32x4*)(out + xi) = o;
  }
}

// ---------------------------------------------------------------------------
extern "C" void kernel_launch(void* const* d_in, const int* in_sizes, int n_in,
                              void* d_out, int out_size, void* d_ws, size_t ws_size,
                              hipStream_t stream)
{
  const float* x     = (const float*)d_in[0];
  const float* A     = (const float*)d_in[1];
  const float* E     = (const float*)d_in[2];
  const float* W     = (const float*)d_in[3];
  const float* cb    = (const float*)d_in[4];
  const float* gamma = (const float*)d_in[5];
  const float* beta  = (const float*)d_in[6];
  float* out = (float*)d_out;

  char* ws = (char*)d_ws;
  const size_t XS_OFF   = 0;                       // 13,107,200 B (bf16 xs)
  const size_t ZB_OFF   = 13107200;                // 13,107,200 B (bf16 zb)
  const size_t WB_OFF   = 26214400;                // 24,576 B (bf16 Wb)
  const size_t A2_OFF   = WB_OFF + 32768;          // 6,144 B
  const size_t BIAS_OFF = A2_OFF + 16384;          // 8,192 B
  const size_t STAT_OFF = BIAS_OFF + 16384;        // 65,536 B (128 x 128 f32)
  ushort_t* xs       = (ushort_t*)(ws + XS_OFF);
  ushort_t* zb       = (ushort_t*)(ws + ZB_OFF);
  ushort_t* wb       = (ushort_t*)(ws + WB_OFF);
  ushort_t* a2       = (ushort_t*)(ws + A2_OFF);
  float*    biastab  = (float*)(ws + BIAS_OFF);
  float*    statsbuf = (float*)(ws + STAT_OFF);

  kwin  <<<dim3(129, N_), 256, 0, stream>>>(x, xs, A, E, cb, W, a2, biastab, wb,
                                            statsbuf);
  kmain <<<dim3(256, N_), 256, 0, stream>>>(xs, wb, a2, biastab, zb, statsbuf);
  kapply<<<dim3(128, N_), 256, 0, stream>>>(zb, x, statsbuf, gamma, beta, out);
}

// Round 8
// 129.407 us; speedup vs baseline: 1.0721x; 1.0721x over previous
//
#include <hip/hip_runtime.h>
#include <hip/hip_cooperative_groups.h>

namespace cg = cooperative_groups;

// ST-GCN fused block for MI355X (gfx950).  FP32 I/O, bf16 at MFMA boundaries.
// Preferred: 2 dispatches: kwin(+prep) -> kmain<true> COOPERATIVE (1024 blocks,
//   LDS 26.6 KB: z-tile zl ALIASED inside dead T1; ONE grid sync; every block
//   reduces the 16 KB statsbuf itself; phase-3 x prefetched pre-sync;
//   coalesced f32x4 out via swizzled zl transpose).
// Fallback: kmain<false> -> zb -> kapply (verified 3-dispatch path).
// xs layout: [n][l][25 v][64 ci] bf16.   statsbuf: 32 copies x 128 f32.

typedef unsigned short ushort_t;
typedef __attribute__((ext_vector_type(8))) short short8;   // 8 x bf16 MFMA frag
typedef __attribute__((ext_vector_type(4))) float f32x4;
typedef __attribute__((ext_vector_type(4))) unsigned short us4;

#define N_  4
#define CI_ 64
#define CO_ 64
#define L_  1024
#define V_  25
#define P_  3
#define KS_ 9
#define NLV 102400.0f   // N_*L_*V_  (BN population count per channel)
#define NREP 32         // stats replication factor
#define TSTR 406        // kwin tile row stride (ushort); u32-friendly

__device__ __forceinline__ float b2f(ushort_t u) {
  union { float f; unsigned int i; } c; c.i = ((unsigned int)u) << 16; return c.f;
}
__device__ __forceinline__ ushort_t f2b(float f) {
  union { float f; unsigned int i; } c; c.f = f;
  unsigned int u = c.i;
  u += 0x7fffu + ((u >> 16) & 1u);      // round-to-nearest-even
  return (ushort_t)(u >> 16);
}

// ---------------------------------------------------------------------------
// kwin: causal 9-wide window-sum along l, fp32 x -> bf16 xs[n][l][25*64].
// block = (chunk of 8 l's x half of ci, n); bx==256 & n==0 does prep.
__global__ __launch_bounds__(256) void kwin(
    const float* __restrict__ x, ushort_t* __restrict__ xs,
    const float* __restrict__ A, const float* __restrict__ E,
    const float* __restrict__ cb, const float* __restrict__ W,
    ushort_t* __restrict__ a2raw, float* __restrict__ biastab,
    ushort_t* __restrict__ wb, float* __restrict__ statsbuf)
{
  const int bx = blockIdx.x;                    // 0..256
  const int n = blockIdx.y;
  const int tid = threadIdx.x;

  if (bx == 256) {                              // ---- prep block ----
    if (n != 0) return;
    __shared__ float colA[P_ * 32];
    if (tid < P_ * 32) {
      int p = tid >> 5, w = tid & 31;
      float s = 0.f;
      if (w < V_)
        for (int v = 0; v < V_; ++v) {
          int idx = (p * V_ + v) * V_ + w;
          s += A[idx] * E[idx];
        }
      colA[tid] = s;
    }
    for (int e = tid; e < 32 * 96; e += 256) {
      int w = e / 96, k = e - w * 96;
      int p = k >> 5, v = k & 31;
      float val = 0.f;
      if (w < V_ && v < V_) {
        int idx = (p * V_ + v) * V_ + w;
        val = A[idx] * E[idx];
      }
      a2raw[e] = f2b(val);
    }
    for (int e = tid; e < 192 * 64; e += 256) wb[e] = f2b(W[e]);
    __syncthreads();
    for (int e = tid; e < 32 * 64; e += 256) {
      int w = e >> 6, c = e & 63;
      float s = 0.f;
      for (int p = 0; p < P_; ++p) s += cb[p * 64 + c] * colA[p * 32 + w];
      biastab[e] = s;
    }
    for (int e = tid; e < NREP * 128; e += 256) statsbuf[e] = 0.f;
    return;
  }

  // ---- window block: 8 l's, 32 ci ----
  const int chunk = bx >> 1, half = bx & 1;     // ci base = 32*half
  __shared__ __align__(16) ushort_t tile[32 * TSTR];  // 26 KB
  const int l0 = chunk * 8;
  const long xn = (long)n * CI_ * L_ * V_ + (long)(half * 32) * (L_ * V_);
  for (int m = tid; m < 3200; m += 256) {       // 32 ci x 400 f32 -> bf16
    int ci = m / 100;
    int j4 = (m - ci * 100) * 4;                // 0..396
    f32x4 d;
    if (chunk == 0 && j4 < 200) {
      d = (f32x4){0.f, 0.f, 0.f, 0.f};          // l < 0 halo (li 0..7)
    } else {
      d = *(const f32x4*)(x + xn + (long)ci * (L_ * V_) + (l0 - 8) * V_ + j4);
    }
    unsigned int p0 = (unsigned int)f2b(d[0]) | ((unsigned int)f2b(d[1]) << 16);
    unsigned int p1 = (unsigned int)f2b(d[2]) | ((unsigned int)f2b(d[3]) << 16);
    *(unsigned int*)(&tile[ci * TSTR + j4])     = p0;
    *(unsigned int*)(&tile[ci * TSTR + j4 + 2]) = p1;
  }
  __syncthreads();
  // sliding window per (v, ci-pair) column; coalesced u32 stores per l_.
  const long xsbase = ((long)n * L_ + l0) * 1600 + half * 32;
  for (int cp = tid; cp < 400; cp += 256) {
    const int v = cp >> 4, ci = (cp & 15) * 2;
    const ushort_t* c0 = &tile[ci * TSTR + v];  // + li*25 steps along l
    const ushort_t* c1 = c0 + TSTR;
    float s0 = 0.f, s1 = 0.f;
#pragma unroll
    for (int li = 0; li < 9; ++li) { s0 += b2f(c0[li * 25]); s1 += b2f(c1[li * 25]); }
    *(unsigned int*)(xs + xsbase + v * 64 + ci) =
        (unsigned int)f2b(s0) | ((unsigned int)f2b(s1) << 16);
#pragma unroll
    for (int l_ = 1; l_ < 8; ++l_) {
      s0 += b2f(c0[(l_ + 8) * 25]) - b2f(c0[(l_ - 1) * 25]);
      s1 += b2f(c1[(l_ + 8) * 25]) - b2f(c1[(l_ - 1) * 25]);
      *(unsigned int*)(xs + xsbase + l_ * 1600 + v * 64 + ci) =
          (unsigned int)f2b(s0) | ((unsigned int)f2b(s1) << 16);
    }
  }
}

// ---------------------------------------------------------------------------
// kmain<COOP>: per-(n, 4 l's) block; single 26.6 KB T1 (only LDS).
//   COOP=true : z regs -> zl (aliased in T1) -> ONE grid sync -> per-block
//               statsbuf reduce -> BN+ReLU+residual, coalesced f32x4 out.
//   COOP=false: z -> zb (global); kapply finishes (verified fallback).
template<bool COOP>
__global__ __launch_bounds__(256, 4) void kmain(
    const ushort_t* __restrict__ xs,      // [n][l][1600] bf16 (L2/L3-hot)
    const ushort_t* __restrict__ Wb,      // [192][64] bf16 (L1-hot)
    const ushort_t* __restrict__ a2,      // [32 w][96 k] bf16 (L1-hot)
    const float*    __restrict__ biastab, // [32 w][64 c] f32 (L1-hot)
    ushort_t*       __restrict__ zb,
    float*          __restrict__ statsbuf,
    const float*    __restrict__ gamma,
    const float*    __restrict__ beta,
    const float*    __restrict__ x,       // residual [n][c][l][v] f32
    float*          __restrict__ out)
{
  const int lb = blockIdx.x;            // 4 l's per block (0..255)
  const int n  = blockIdx.y;
  const int tid = threadIdx.x, lane = tid & 63, wv = tid >> 6;
  const int m16 = lane & 15, quad = lane >> 4;

  __shared__ __align__(16) ushort_t T1[13312];   // [l_][c][104]  26.6 KB
  // COOP aliases (T1 dead by then): zl = T1[0..6800) (100 rows x 68 cols),
  // part = f32 @ T1[8192], scsh = f32 @ T1[8704].

  // hoist Wb A-frags once (reused by both pairs)
  short8 af[3][2];
#pragma unroll
  for (int i = 0; i < 3; ++i) {
    const ushort_t* wrow = Wb + ((wv * 3 + i) * 16 + m16) * 64 + quad * 8;
    af[i][0] = *(const short8*)(wrow);
    af[i][1] = *(const short8*)(wrow + 32);
  }

  const ushort_t* xsb = xs + ((long)n * L_ + 4 * lb) * 1600;
  const int cbase = wv * 16 + quad * 4;
  float s1[4] = {0.f, 0.f, 0.f, 0.f}, s2[4] = {0.f, 0.f, 0.f, 0.f};
  us4 zpack[2][2][2];                   // [pair][l_][nt] — COOP keeps z in regs

#pragma unroll
  for (int pair = 0; pair < 2; ++pair) {
    // ---- stage 1: B-frags direct from global xs (predicated zero v>=25) ----
    short8 bfr[4][2];
#pragma unroll
    for (int nt = 0; nt < 4; ++nt) {
      const int v = (nt & 1) * 16 + m16;
      const int l_ = pair * 2 + (nt >> 1);
#pragma unroll
      for (int ks = 0; ks < 2; ++ks) {
        short8 t = (short8){0, 0, 0, 0, 0, 0, 0, 0};
        if (v < V_)
          t = *(const short8*)(xsb + l_ * 1600 + v * 64 + ks * 32 + quad * 8);
        bfr[nt][ks] = t;
      }
    }

    f32x4 acc1[3][4];
#pragma unroll
    for (int i = 0; i < 3; ++i)
#pragma unroll
      for (int j = 0; j < 4; ++j) acc1[i][j] = (f32x4){0.f, 0.f, 0.f, 0.f};

#pragma unroll
    for (int i = 0; i < 3; ++i)
#pragma unroll
      for (int nt = 0; nt < 4; ++nt) {
        acc1[i][nt] = __builtin_amdgcn_mfma_f32_16x16x32_bf16(af[i][0], bfr[nt][0], acc1[i][nt], 0, 0, 0);
        acc1[i][nt] = __builtin_amdgcn_mfma_f32_16x16x32_bf16(af[i][1], bfr[nt][1], acc1[i][nt], 0, 0, 0);
      }

    if (pair) __syncthreads();          // prior pair's T1 reads complete
    // repack t1 -> T1[l_][c][p*32+v]  (D: row = quad*4+r, col = m16)
#pragma unroll
    for (int i = 0; i < 3; ++i) {
      const int mt = wv * 3 + i;
#pragma unroll
      for (int nt = 0; nt < 4; ++nt) {
        const int l_ = nt >> 1;
        const int col = (nt & 1) * 16 + m16;
#pragma unroll
        for (int r = 0; r < 4; ++r) {
          int k = mt * 16 + quad * 4 + r;        // k = p*64 + c
          T1[l_ * 6656 + (k & 63) * 104 + (k >> 6) * 32 + col] = f2b(acc1[i][nt][r]);
        }
      }
    }
    __syncthreads();

    // ---- stage 2: 12 MFMA; a2 B-frags loaded per pair (global, L1-hot) ----
    short8 bfr2[2][3];
#pragma unroll
    for (int nt = 0; nt < 2; ++nt)
#pragma unroll
      for (int ks = 0; ks < 3; ++ks)
        bfr2[nt][ks] = *(const short8*)(a2 + (nt * 16 + m16) * 96 + ks * 32 + quad * 8);

    f32x4 acc2[2][2];
#pragma unroll
    for (int l_ = 0; l_ < 2; ++l_)
#pragma unroll
      for (int nt = 0; nt < 2; ++nt) acc2[l_][nt] = (f32x4){0.f, 0.f, 0.f, 0.f};

#pragma unroll
    for (int l_ = 0; l_ < 2; ++l_)
#pragma unroll
      for (int ks = 0; ks < 3; ++ks) {
        short8 afT = *(const short8*)(&T1[l_ * 6656 + (wv * 16 + m16) * 104 + ks * 32 + quad * 8]);
        acc2[l_][0] = __builtin_amdgcn_mfma_f32_16x16x32_bf16(afT, bfr2[0][ks], acc2[l_][0], 0, 0, 0);
        acc2[l_][1] = __builtin_amdgcn_mfma_f32_16x16x32_bf16(afT, bfr2[1][ks], acc2[l_][1], 0, 0, 0);
      }

    // epilogue: + cnt(l)*bias (float4); z -> regs (COOP) or zb (fallback)
#pragma unroll
    for (int l_ = 0; l_ < 2; ++l_) {
      const int l = 4 * lb + pair * 2 + l_;
      const float cnt = (float)(l + 1 < KS_ ? l + 1 : KS_);
#pragma unroll
      for (int nt = 0; nt < 2; ++nt) {
        const int w = nt * 16 + m16;
        if (w < V_) {
          f32x4 bias = *(const f32x4*)(biastab + w * 64 + cbase);
          us4 pack;
#pragma unroll
          for (int r = 0; r < 4; ++r) {
            pack[r] = f2b(acc2[l_][nt][r] + cnt * bias[r]);
            float zr = b2f(pack[r]);            // stats on the stored value
            s1[r] += zr; s2[r] += zr * zr;
          }
          if constexpr (COOP)
            zpack[pair][l_][nt] = pack;
          else
            *(us4*)(&zb[(((long)(n * L_ + l) * V_ + w) << 6) + cbase]) = pack;
        }
      }
    }
  }
  // in-quad reduction over m16 (lanes of a quad share channels cbase..cbase+3)
#pragma unroll
  for (int off = 1; off < 16; off <<= 1) {
#pragma unroll
    for (int r = 0; r < 4; ++r) {
      s1[r] += __shfl_xor(s1[r], off, 64);
      s2[r] += __shfl_xor(s2[r], off, 64);
    }
  }
  if (m16 == 0) {
    float* sb = statsbuf + ((n * 256 + lb) & (NREP - 1)) * 128;
#pragma unroll
    for (int r = 0; r < 4; ++r) {
      atomicAdd(&sb[cbase + r], s1[r]);
      atomicAdd(&sb[64 + cbase + r], s2[r]);
    }
  }

  if constexpr (COOP) {
    // ---- park z tile in zl (aliases T1; T1 MFMA reads are done) ----
    __syncthreads();
    ushort_t* zl = T1;                  // [rr][c^e], 100 x 68
#pragma unroll
    for (int pair = 0; pair < 2; ++pair)
#pragma unroll
      for (int l_ = 0; l_ < 2; ++l_)
#pragma unroll
        for (int nt = 0; nt < 2; ++nt) {
          const int w = nt * 16 + m16;
          if (w < V_) {
            const int rr = (pair * 2 + l_) * 25 + w;
            const int e = ((rr >> 2) & 31) << 1;
            const us4 pk = zpack[pair][l_][nt];
            *(unsigned int*)(&zl[rr * 68 + (cbase ^ e)]) =
                (unsigned int)pk[0] | ((unsigned int)pk[1] << 16);
            *(unsigned int*)(&zl[rr * 68 + ((cbase + 2) ^ e)]) =
                (unsigned int)pk[2] | ((unsigned int)pk[3] << 16);
          }
        }

    // ---- prefetch phase-3 residual x (hides HBM under sync+reduce) ----
    const long obase = (long)(n * 64) * (L_ * V_) + lb * 100;
    f32x4 xv[7];
#pragma unroll
    for (int i = 0; i < 7; ++i) {
      const int m = tid + i * 256;
      if (m < 1600) {
        const int c = m / 25, q = m - c * 25;
        xv[i] = *(const f32x4*)(x + obase + (long)c * (L_ * V_) + q * 4);
      }
    }

    cg::this_grid().sync();             // all stats atomics done grid-wide

    // ---- every block reduces the 16 KB statsbuf (L2/L3-hot) ----
    float* part = (float*)&T1[8192];
    float* scsh = (float*)&T1[8704];
    {
      const int slot = tid & 127, hf = tid >> 7;
      float a = 0.f;
      for (int k = hf; k < NREP; k += 2)
        a += __hip_atomic_load(&statsbuf[k * 128 + slot],
                               __ATOMIC_RELAXED, __HIP_MEMORY_SCOPE_AGENT);
      part[tid] = a;
    }
    __syncthreads();
    if (tid < 64) {
      const float inv = 1.0f / NLV;
      float s    = part[tid]      + part[128 + tid];
      float sq   = part[64 + tid] + part[192 + tid];
      float mean = s * inv;
      float var  = sq * inv - mean * mean;
      float rstd = rsqrtf(var + 1e-5f);
      float g = gamma[tid];
      scsh[tid]      = rstd * g;
      scsh[64 + tid] = beta[tid] - mean * rstd * g;
    }
    __syncthreads();

    // ---- phase 3: BN + ReLU + residual, coalesced f32x4 out ----
#pragma unroll
    for (int i = 0; i < 7; ++i) {
      const int m = tid + i * 256;
      if (m < 1600) {
        const int c = m / 25, q = m - c * 25, rr = q * 4;
        const int e = q << 1;           // ((rr>>2)&31)<<1, q<25
        const long xi = obase + (long)c * (L_ * V_) + rr;
        const float scc = scsh[c], shc = scsh[64 + c];
        f32x4 o;
#pragma unroll
        for (int j = 0; j < 4; ++j) {
          float z = b2f(zl[(rr + j) * 68 + (c ^ e)]);
          float y = fmaxf(z * scc + shc, 0.f);
          o[j] = fmaxf(y + xv[i][j], 0.f);
        }
        *(f32x4*)(out + xi) = o;
      }
    }
  }
}

// ---------------------------------------------------------------------------
// kapply (fallback only): reduce statsbuf copies -> mean/var, then
// out[n,c,l,v] = relu(relu((z-mean)*rstd*g+b) + x).  8 l's per block, f32x4.
__global__ __launch_bounds__(256) void kapply(
    const ushort_t* __restrict__ zb, const float* __restrict__ x,
    const float* __restrict__ statsbuf,
    const float* __restrict__ gamma, const float* __restrict__ beta,
    float* __restrict__ out)
{
  const int n = blockIdx.y, chunk = blockIdx.x;   // 8 l's per block
  const int tid = threadIdx.x;
  __shared__ __align__(16) ushort_t zl[200 * 66]; // 26.4 KB transpose staging
  __shared__ f32x4 red[8][32];
  __shared__ float sc[64], sh[64];
  const long zbase = (long)((n * L_ + chunk * 8) * V_) * 64;   // 12800 elems
  for (int m = tid; m < 6400; m += 256) {         // u32 = 2 bf16, swizzled col
    const int row = m >> 5, c2 = (m & 31) * 2;
    const int cs = c2 ^ (((row >> 2) & 31) << 1);
    *(unsigned int*)(&zl[row * 66 + cs]) = ((const unsigned int*)(zb + zbase))[m];
  }
  {
    const int s4 = tid & 31, grp = tid >> 5;      // 8 groups x 32 f32x4 slots
    const f32x4* sb4 = (const f32x4*)statsbuf;
    f32x4 a = (f32x4){0.f, 0.f, 0.f, 0.f};
    for (int k = grp; k < NREP; k += 8) {
      f32x4 v = sb4[k * 32 + s4];
      a[0] += v[0]; a[1] += v[1]; a[2] += v[2]; a[3] += v[3];
    }
    red[grp][s4] = a;
  }
  __syncthreads();
  if (tid < 64) {
    const float inv = 1.0f / NLV;
    float s = 0.f, sq = 0.f;
#pragma unroll
    for (int g = 0; g < 8; ++g) {
      s  += red[g][tid >> 2][tid & 3];
      sq += red[g][16 + (tid >> 2)][tid & 3];
    }
    float mean = s * inv;
    float var  = sq * inv - mean * mean;
    float rstd = rsqrtf(var + 1e-5f);
    float g = gamma[tid];
    sc[tid] = rstd * g;
    sh[tid] = beta[tid] - mean * rstd * g;
  }
  __syncthreads();
  const long obase = ((long)(n * 64) * L_ + chunk * 8) * V_;   // + c*25600 + rr
  for (int m = tid; m < 3200; m += 256) {
    int c = m / 50, q = m - c * 50, rr = q * 4;   // rr = 4-aligned l*25+v
    const int e = ((q & 31) << 1);
    long xi = obase + (long)c * (L_ * V_) + rr;
    f32x4 xv = *(const f32x4*)(x + xi);
    const float scc = sc[c], shc = sh[c];
    f32x4 o;
#pragma unroll
    for (int j = 0; j < 4; ++j) {
      float z = b2f(zl[(rr + j) * 66 + (c ^ e)]);
      float y = fmaxf(z * scc + shc, 0.f);
      o[j] = fmaxf(y + xv[j], 0.f);
    }
    *(f32x4*)(out + xi) = o;
  }
}

// ---------------------------------------------------------------------------
extern "C" void kernel_launch(void* const* d_in, const int* in_sizes, int n_in,
                              void* d_out, int out_size, void* d_ws, size_t ws_size,
                              hipStream_t stream)
{
  const float* x     = (const float*)d_in[0];
  const float* A     = (const float*)d_in[1];
  const float* E     = (const float*)d_in[2];
  const float* W     = (const float*)d_in[3];
  const float* cb    = (const float*)d_in[4];
  const float* gamma = (const float*)d_in[5];
  const float* beta  = (const float*)d_in[6];
  float* out = (float*)d_out;

  char* ws = (char*)d_ws;
  const size_t XS_OFF   = 0;                       // 13,107,200 B (bf16 xs)
  const size_t ZB_OFF   = 13107200;                // 13,107,200 B (bf16 zb, fallback)
  const size_t WB_OFF   = 26214400;                // 24,576 B (bf16 Wb)
  const size_t A2_OFF   = WB_OFF + 32768;          // 6,144 B
  const size_t BIAS_OFF = A2_OFF + 16384;          // 8,192 B
  const size_t STAT_OFF = BIAS_OFF + 16384;        // 16,384 B (32 x 128 f32)
  ushort_t* xs       = (ushort_t*)(ws + XS_OFF);
  ushort_t* zb       = (ushort_t*)(ws + ZB_OFF);
  ushort_t* wb       = (ushort_t*)(ws + WB_OFF);
  ushort_t* a2       = (ushort_t*)(ws + A2_OFF);
  float*    biastab  = (float*)(ws + BIAS_OFF);
  float*    statsbuf = (float*)(ws + STAT_OFF);

  kwin<<<dim3(257, N_), 256, 0, stream>>>(x, xs, A, E, cb, W, a2, biastab, wb,
                                          statsbuf);

  // validate cooperative residency (host-side query; capture-safe)
  auto kcoop = kmain<true>;
  int maxb = 0;
  hipError_t qe = hipOccupancyMaxActiveBlocksPerMultiprocessor(&maxb, kcoop, 256, 0);
  bool coop = (qe == hipSuccess) && (maxb >= 4);

  if (coop) {
    void* args[] = {&xs, &wb, &a2, &biastab, &zb, &statsbuf,
                    (void*)&gamma, (void*)&beta, (void*)&x, &out};
    hipError_t le = hipLaunchCooperativeKernel((const void*)kcoop,
                                               dim3(256, N_), dim3(256),
                                               args, 0, stream);
    if (le != hipSuccess) coop = false;
  }
  if (!coop) {                          // verified 3-dispatch fallback
    kmain<false><<<dim3(256, N_), 256, 0, stream>>>(
        xs, wb, a2, biastab, zb, statsbuf, gamma, beta, x, out);
    kapply<<<dim3(128, N_), 256, 0, stream>>>(zb, x, statsbuf, gamma, beta, out);
  }
}